// Round 17
// baseline (72.000 us; speedup 1.0000x reference)
//
#include <hip/hip_runtime.h>
#include <math.h>

#define IN_CH 64
#define OUT_CH 64
#define M1 32
#define M2 32
#define HH 512
#define WW 512

// ---------------- workspace layout (floats) ----------------
// F   : [512][64]  cols 0..31 = cos(2pi k h/512), cols 32..63 = sin(...)
// FA2 : [256][64]  folded stage-A table. col j<32: re, j>=32: im; mode k=kperm(j&31);
//                  value = cos(2pi k w'/512) (re) or -sin (im). kperm(q)= q<16 ? 2q : 2(q-16)+1.
// GE2 : [64][256]  folded stage-E table. row c: c<16 re k=2c; 16..31 im k=2(c-16);
//                  32..47 re k=2(c-32)+1; 48..63 im k=2(c-48)+1. cos (re) / -sin (im).
// GT  : [64][512]  row j<32: cos(2pi j t/512); row j>=32: -sin(...)
// XFp : [64 i][16 ht][2 reim][32 kx][32 ky']  partial h-DFT (32-row h-tiles)
// Gp  : [2 ic][64 o][32 kx][32 ky][2]  partial channel-mix (REAL ky order)
static const size_t OFF_F   = 0;
static const size_t OFF_FA2 = 32768;
static const size_t OFF_GE2 = 49152;
static const size_t OFF_GT  = 65536;
static const size_t OFF_XFP = 98304;
static const size_t OFF_GP  = OFF_XFP + (size_t)64*16*2048;

__device__ __forceinline__ void gload16(const float* g, float* l) {
    __builtin_amdgcn_global_load_lds(
        (const __attribute__((address_space(1))) void*)g,
        (__attribute__((address_space(3))) void*)l, 16, 0, 0);
}

__global__ void build_table(float* __restrict__ F, float* __restrict__ FA2,
                            float* __restrict__ GE2, float* __restrict__ GT) {
    int idx = blockIdx.x * 256 + threadIdx.x;      // 0..32767
    const float c0 = 6.283185307179586f / 512.0f;
    {   // F + GT
        int w = idx >> 6, j = idx & 63, k = j & 31;
        int m = (k * w) & 511;
        float s, c;
        sincosf(c0 * (float)m, &s, &c);
        F[idx] = (j < 32) ? c : s;
        GT[(size_t)j * 512 + w] = (j < 32) ? c : -s;
    }
    if (idx < 16384) {   // FA2 [256][64]
        int wp = idx >> 6, j = idx & 63, q = j & 31;
        int k = (q < 16) ? 2 * q : 2 * (q - 16) + 1;
        int m = (k * wp) & 511;
        float s, c;
        sincosf(c0 * (float)m, &s, &c);
        FA2[idx] = (j < 32) ? c : -s;
    }
    if (idx < 16384) {   // GE2 [64][256]
        int cc = idx >> 8, wp = idx & 255;
        int base = cc & 15, parity = (cc >> 5) & 1, isIm = (cc >> 4) & 1;
        int k = 2 * base + parity;
        int m = (k * wp) & 511;
        float s, c;
        sincosf(c0 * (float)m, &s, &c);
        GE2[idx] = isIm ? -s : c;
    }
}

// Fused A+B, BM=32, grid 1024 (i = bid>>4, ht = bid&15), 4 blocks/CU.
// Phase A: Xw[32][64 j'] over K=256 in 8 chunks of 32; acc = 2 rows x 4 cols/thread.
// e/o tiles [32][36] (stride-36: A-reads hit distinct banks); FA2 dbuf in bs via
// gload16, x chunk prefetched to regs after each barrier (full compute phase to land).
// Phase B: 32-hh partial h-DFT, XFp 16 partials per i.
__global__ __launch_bounds__(256, 4) void fusedAB(const float* __restrict__ x,
                                                  const float* __restrict__ FA2,
                                                  const float* __restrict__ GT,
                                                  float* __restrict__ XFp) {
    __shared__ __align__(16) float xeo[2304];   // e [32][36] @0, o @1152; later xw [32][68]
    __shared__ __align__(16) float bs[4096];    // FA2 dbuf [32][64] @0/@2048; later gt [64][36]
    int t = threadIdx.x, tx = t & 15, ty = t >> 4;
    int i = blockIdx.x >> 4, ht = blockIdx.x & 15;
    int h0 = ht * 32;
    int srow = t >> 3, scol = (t & 7) * 4;      // staging: 8 threads/row, coalesced 128B rows

    const float* xb = &x[((size_t)i * 512 + h0 + srow) * 512 + scol];
    float4 ra, rb, gt0, gt1;

    // prologue: x chunk0 -> regs; FA2 chunk0 -> bs[0]
    ra = *(const float4*)(xb);
    rb = *(const float4*)(xb + 256);
    gload16(FA2 + t * 4, &bs[t * 4]);
    gload16(FA2 + 1024 + t * 4, &bs[1024 + t * 4]);

    float4 acc0 = make_float4(0.f, 0.f, 0.f, 0.f);
    float4 acc1 = make_float4(0.f, 0.f, 0.f, 0.f);
    const float* xsb = &xeo[(tx & 4) ? 1152 : 0];   // cols 16..31,48..63: odd-k -> o
    for (int tt = 0; tt < 8; ++tt) {
        if (tt) __syncthreads();     // A: readers of chunk tt-1 done
        *(float4*)&xeo[srow * 36 + scol] =
            make_float4(ra.x + rb.x, ra.y + rb.y, ra.z + rb.z, ra.w + rb.w);
        *(float4*)&xeo[1152 + srow * 36 + scol] =
            make_float4(ra.x - rb.x, ra.y - rb.y, ra.z - rb.z, ra.w - rb.w);
        __syncthreads();             // B: e/o visible; bs chunk tt drained
        int cur = (tt & 1) << 11;
        if (tt < 7) {                // issue next chunk's loads AFTER the barrier
            const float* xn = xb + (tt + 1) * 32;
            ra = *(const float4*)(xn);
            rb = *(const float4*)(xn + 256);
            int nxt = ((tt + 1) & 1) << 11;
            gload16(FA2 + (size_t)(tt + 1) * 2048 + t * 4, &bs[nxt + t * 4]);
            gload16(FA2 + (size_t)(tt + 1) * 2048 + 1024 + t * 4, &bs[nxt + 1024 + t * 4]);
        } else {                     // prefetch GT slice ([64][32]) for phase B
            int f0 = t * 4, f1 = 1024 + t * 4;
            gt0 = *(const float4*)&GT[(size_t)(f0 >> 5) * 512 + h0 + (f0 & 31)];
            gt1 = *(const float4*)&GT[(size_t)(f1 >> 5) * 512 + h0 + (f1 & 31)];
        }
#pragma unroll
        for (int k0 = 0; k0 < 32; k0 += 4) {
            float4 av0 = *(const float4*)&xsb[ty * 36 + k0];
            float4 av1 = *(const float4*)&xsb[(16 + ty) * 36 + k0];
            float4 bv[4];
#pragma unroll
            for (int kk = 0; kk < 4; ++kk)
                bv[kk] = *(const float4*)&bs[cur + (k0 + kk) * 64 + tx * 4];
#pragma unroll
            for (int kk = 0; kk < 4; ++kk) {
                float x0 = (kk == 0) ? av0.x : (kk == 1) ? av0.y
                         : (kk == 2) ? av0.z : av0.w;
                float x1 = (kk == 0) ? av1.x : (kk == 1) ? av1.y
                         : (kk == 2) ? av1.z : av1.w;
                acc0.x = __builtin_fmaf(x0, bv[kk].x, acc0.x);
                acc0.y = __builtin_fmaf(x0, bv[kk].y, acc0.y);
                acc0.z = __builtin_fmaf(x0, bv[kk].z, acc0.z);
                acc0.w = __builtin_fmaf(x0, bv[kk].w, acc0.w);
                acc1.x = __builtin_fmaf(x1, bv[kk].x, acc1.x);
                acc1.y = __builtin_fmaf(x1, bv[kk].y, acc1.y);
                acc1.z = __builtin_fmaf(x1, bv[kk].z, acc1.z);
                acc1.w = __builtin_fmaf(x1, bv[kk].w, acc1.w);
            }
        }
    }
    __syncthreads();

    // store Xw (rows ty and 16+ty) into xeo [32][68]; gt regs into bs [64][36]
    *(float4*)&xeo[ty * 68 + tx * 4]        = acc0;
    *(float4*)&xeo[(16 + ty) * 68 + tx * 4] = acc1;
    {
        int f0 = t * 4, f1 = 1024 + t * 4;
        *(float4*)&bs[(f0 >> 5) * 36 + (f0 & 31)] = gt0;
        *(float4*)&bs[(f1 >> 5) * 36 + (f1 & 31)] = gt1;
    }
    __syncthreads();

    // Phase B over 32 hh
    int kx = t >> 3, kg = t & 7;
    float rr[4] = {0.f, 0.f, 0.f, 0.f};
    float ii[4] = {0.f, 0.f, 0.f, 0.f};
#pragma unroll 4
    for (int hh = 0; hh < 32; ++hh) {
        float cv = bs[kx * 36 + hh];
        float sv = bs[(kx + 32) * 36 + hh];          // = -sin
        float4 xr4 = *(const float4*)&xeo[hh * 68 + kg * 4];
        float4 xi4 = *(const float4*)&xeo[hh * 68 + 32 + kg * 4];
        rr[0] = __builtin_fmaf(xr4.x, cv, rr[0]); rr[0] = __builtin_fmaf(xi4.x, -sv, rr[0]);
        rr[1] = __builtin_fmaf(xr4.y, cv, rr[1]); rr[1] = __builtin_fmaf(xi4.y, -sv, rr[1]);
        rr[2] = __builtin_fmaf(xr4.z, cv, rr[2]); rr[2] = __builtin_fmaf(xi4.z, -sv, rr[2]);
        rr[3] = __builtin_fmaf(xr4.w, cv, rr[3]); rr[3] = __builtin_fmaf(xi4.w, -sv, rr[3]);
        ii[0] = __builtin_fmaf(xi4.x, cv, ii[0]); ii[0] = __builtin_fmaf(xr4.x, sv, ii[0]);
        ii[1] = __builtin_fmaf(xi4.y, cv, ii[1]); ii[1] = __builtin_fmaf(xr4.y, sv, ii[1]);
        ii[2] = __builtin_fmaf(xi4.z, cv, ii[2]); ii[2] = __builtin_fmaf(xr4.z, sv, ii[2]);
        ii[3] = __builtin_fmaf(xi4.w, cv, ii[3]); ii[3] = __builtin_fmaf(xr4.w, sv, ii[3]);
    }
    size_t base = ((size_t)i * 16 + ht) * 2048;
    *(float4*)&XFp[base + t * 4]        = make_float4(rr[0], rr[1], rr[2], rr[3]);
    *(float4*)&XFp[base + 1024 + t * 4] = make_float4(ii[0], ii[1], ii[2], ii[3]);
}

// Stage C: partial channel mix, i split in 2. grid 512. float4 ht-sum (16 partials).
__global__ __launch_bounds__(256) void stageC(const float* __restrict__ XFp,
                                              const float* __restrict__ Wr,
                                              const float* __restrict__ Wi,
                                              float* __restrict__ Gp) {
    __shared__ float sxr[32][33];   // [ky'][i']
    __shared__ float sxi[32][33];
    int t = threadIdx.x;
    int kx = blockIdx.x & 31, oc = (blockIdx.x >> 5) & 7, ic = blockIdx.x >> 8;
    {
        int ip = t >> 3, kys4 = t & 7;       // ip 0..31, ky'-quad 0..7
        int i = ic * 32 + ip;
        float4 sr = make_float4(0.f, 0.f, 0.f, 0.f);
        float4 si = make_float4(0.f, 0.f, 0.f, 0.f);
#pragma unroll
        for (int htl = 0; htl < 16; ++htl) {
            size_t base = ((size_t)i * 16 + htl) * 2048 + kx * 32 + kys4 * 4;
            float4 r4 = *(const float4*)&XFp[base];
            float4 i4 = *(const float4*)&XFp[base + 1024];
            sr.x += r4.x; sr.y += r4.y; sr.z += r4.z; sr.w += r4.w;
            si.x += i4.x; si.y += i4.y; si.z += i4.z; si.w += i4.w;
        }
        sxr[kys4 * 4 + 0][ip] = sr.x; sxr[kys4 * 4 + 1][ip] = sr.y;
        sxr[kys4 * 4 + 2][ip] = sr.z; sxr[kys4 * 4 + 3][ip] = sr.w;
        sxi[kys4 * 4 + 0][ip] = si.x; sxi[kys4 * 4 + 1][ip] = si.y;
        sxi[kys4 * 4 + 2][ip] = si.z; sxi[kys4 * 4 + 3][ip] = si.w;
    }
    __syncthreads();
    int ky = t & 31, ol = t >> 5;            // REAL ky
    int kyp = (ky & 1) ? 16 + (ky >> 1) : (ky >> 1);
    int o = oc * 8 + ol;
    float lr = 0.f, li = 0.f;
#pragma unroll 4
    for (int ip = 0; ip < 32; ++ip) {
        float a = sxr[kyp][ip];
        float b = sxi[kyp][ip];
        size_t widx = ((size_t)(ic * 32 + ip) * 64 + o) * 1024 + kx * 32 + ky;
        float wrv = Wr[widx];
        float wiv = Wi[widx];
        lr = __builtin_fmaf(a, wrv, lr); lr = __builtin_fmaf(-b, wiv, lr);
        li = __builtin_fmaf(a, wiv, li); li = __builtin_fmaf(b, wrv, li);
    }
    size_t gidx = ((size_t)ic * 65536 + (size_t)o * 1024 + kx * 32 + ky) * 2;
    Gp[gidx]     = lr;
    Gp[gidx + 1] = li;
}

// Fused (reduceG +) D + E. grid 512: o = bid>>3, ht = bid&7. (R7/R16 verbatim)
__global__ __launch_bounds__(256) void fusedDE(const float* __restrict__ Fc,
                                               const float* __restrict__ Gp,
                                               const float* __restrict__ GE2,
                                               float* __restrict__ out) {
    __shared__ __align__(16) float as[4096];   // F-tile (src-swizzled), then Z (XOR-swizzled)
    __shared__ __align__(16) float bs[4096];   // G [64m][64j'], then GE2 tiles
    int t = threadIdx.x, tx = t & 15, ty = t >> 4;
    int o = blockIdx.x >> 3, ht = blockIdx.x & 7;
    int sw = (ty & 3) << 2;

    const float2* gp2 = (const float2*)Gp;
#pragma unroll
    for (int q = 0; q < 4; ++q) {
        int iq = q * 256 + t;                 // 0..1023 = kx*32+ky (REAL ky)
        int ky = iq & 31, kx = iq >> 5;
        float2 g0 = gp2[(size_t)o * 1024 + iq];
        float2 g1 = gp2[(size_t)65536 + (size_t)o * 1024 + iq];
        float sc = ((ky == 0) ? 1.0f : 2.0f) * (1.0f / 262144.0f);
        float lr = (g0.x + g1.x) * sc;
        float li = (g0.y + g1.y) * sc;
        int pp = ky & 1, qq = ky >> 1;
        int colR = pp * 32 + qq, colI = pp * 32 + 16 + qq;
        bs[kx * 64 + colR]        = lr;
        bs[(32 + kx) * 64 + colR] = -li;
        bs[kx * 64 + colI]        = li;
        bs[(32 + kx) * 64 + colI] = lr;
    }
#pragma unroll
    for (int p = 0; p < 4; ++p) {
        int flat = p * 1024 + t * 4;
        int s16 = flat >> 2;
        int row = s16 >> 4, cp = s16 & 15;
        int cg = cp ^ ((row >> 2) & 3);
        gload16(Fc + (size_t)(ht * 64 + row) * 64 + cg * 4, &as[flat]);
    }
    __syncthreads();

    float acc[4][4] = {};
#pragma unroll 4
    for (int k0 = 0; k0 < 64; k0 += 4) {
        int ka = k0 ^ sw;
        float4 av[4], bv[4];
#pragma unroll
        for (int r = 0; r < 4; ++r)
            av[r] = *(const float4*)&as[(ty * 4 + r) * 64 + ka];
#pragma unroll
        for (int kk = 0; kk < 4; ++kk)
            bv[kk] = *(const float4*)&bs[(k0 + kk) * 64 + tx * 4];
#pragma unroll
        for (int kk = 0; kk < 4; ++kk)
#pragma unroll
            for (int r = 0; r < 4; ++r) {
                float xk = (kk == 0) ? av[r].x : (kk == 1) ? av[r].y
                         : (kk == 2) ? av[r].z : av[r].w;
                acc[r][0] = __builtin_fmaf(xk, bv[kk].x, acc[r][0]);
                acc[r][1] = __builtin_fmaf(xk, bv[kk].y, acc[r][1]);
                acc[r][2] = __builtin_fmaf(xk, bv[kk].z, acc[r][2]);
                acc[r][3] = __builtin_fmaf(xk, bv[kk].w, acc[r][3]);
            }
    }
    __syncthreads();

#pragma unroll
    for (int r = 0; r < 4; ++r) {
        int row = ty * 4 + r;
        int cg = tx ^ ((row >> 2) & 3);
        *(float4*)&as[row * 64 + cg * 4] =
            make_float4(acc[r][0], acc[r][1], acc[r][2], acc[r][3]);
    }

    for (int cb = 0; cb < 4; ++cb) {
        __syncthreads();
#pragma unroll
        for (int p = 0; p < 4; ++p) {
            int flat = p * 1024 + t * 4;
            int brow = flat >> 6, bcol = flat & 63;
            gload16(GE2 + (size_t)brow * 256 + cb * 64 + bcol, &bs[flat]);
        }
        __syncthreads();
        float pa[4][4] = {}, pb[4][4] = {};
#pragma unroll 4
        for (int k0 = 0; k0 < 32; k0 += 4) {
            int kae = k0 ^ sw, kao = 32 + (k0 ^ sw);
            float4 av[4], bv[4], aw[4], bw[4];
#pragma unroll
            for (int r = 0; r < 4; ++r) {
                av[r] = *(const float4*)&as[(ty * 4 + r) * 64 + kae];
                aw[r] = *(const float4*)&as[(ty * 4 + r) * 64 + kao];
            }
#pragma unroll
            for (int kk = 0; kk < 4; ++kk) {
                bv[kk] = *(const float4*)&bs[(k0 + kk) * 64 + tx * 4];
                bw[kk] = *(const float4*)&bs[(32 + k0 + kk) * 64 + tx * 4];
            }
#pragma unroll
            for (int kk = 0; kk < 4; ++kk)
#pragma unroll
                for (int r = 0; r < 4; ++r) {
                    float xe = (kk == 0) ? av[r].x : (kk == 1) ? av[r].y
                             : (kk == 2) ? av[r].z : av[r].w;
                    float xo = (kk == 0) ? aw[r].x : (kk == 1) ? aw[r].y
                             : (kk == 2) ? aw[r].z : aw[r].w;
                    pa[r][0] = __builtin_fmaf(xe, bv[kk].x, pa[r][0]);
                    pa[r][1] = __builtin_fmaf(xe, bv[kk].y, pa[r][1]);
                    pa[r][2] = __builtin_fmaf(xe, bv[kk].z, pa[r][2]);
                    pa[r][3] = __builtin_fmaf(xe, bv[kk].w, pa[r][3]);
                    pb[r][0] = __builtin_fmaf(xo, bw[kk].x, pb[r][0]);
                    pb[r][1] = __builtin_fmaf(xo, bw[kk].y, pb[r][1]);
                    pb[r][2] = __builtin_fmaf(xo, bw[kk].z, pb[r][2]);
                    pb[r][3] = __builtin_fmaf(xo, bw[kk].w, pb[r][3]);
                }
        }
#pragma unroll
        for (int r = 0; r < 4; ++r) {
            float* orow = out + (size_t)(o * 512 + ht * 64 + ty * 4 + r) * 512;
            *(float4*)&orow[cb * 64 + tx * 4] =
                make_float4(pa[r][0] + pb[r][0], pa[r][1] + pb[r][1],
                            pa[r][2] + pb[r][2], pa[r][3] + pb[r][3]);
            *(float4*)&orow[256 + cb * 64 + tx * 4] =
                make_float4(pa[r][0] - pb[r][0], pa[r][1] - pb[r][1],
                            pa[r][2] - pb[r][2], pa[r][3] - pb[r][3]);
        }
    }
}

extern "C" void kernel_launch(void* const* d_in, const int* in_sizes, int n_in,
                              void* d_out, int out_size, void* d_ws, size_t ws_size,
                              hipStream_t stream) {
    const float* x  = (const float*)d_in[0];
    const float* Wr = (const float*)d_in[1];
    const float* Wi = (const float*)d_in[2];
    float* out = (float*)d_out;
    float* ws  = (float*)d_ws;

    float* F   = ws + OFF_F;
    float* FA2 = ws + OFF_FA2;
    float* GE2 = ws + OFF_GE2;
    float* GT  = ws + OFF_GT;
    float* XFp = ws + OFF_XFP;
    float* Gp  = ws + OFF_GP;

    build_table<<<128, 256, 0, stream>>>(F, FA2, GE2, GT);
    fusedAB<<<1024, 256, 0, stream>>>(x, FA2, GT, XFp);
    stageC<<<512, 256, 0, stream>>>(XFp, Wr, Wi, Gp);
    fusedDE<<<512, 256, 0, stream>>>(F, Gp, GE2, out);
}